// Round 8
// baseline (125.806 us; speedup 1.0000x reference)
//
#include <hip/hip_runtime.h>

// out[b,o] = p[b]*q[o] + bias[o]
//   p[b] = prod_i inputs[b,i];  q = (1^T * prod_i C_i) @ projection
// K1:  256 WGs: tree L1 (1024 cores -> 256 mats) + p-products; zeroes flag.
// K4F: 256 WGs, fused k2+k4 (R7 post-mortem: per-kernel compute is small;
//      serial dispatch boundaries + k2's 16-WG latency island are the cost).
//      WGs 0-15 produce the 16 level-2 mats (release fence + atomicAdd);
//      all WGs spin to flag==16 (acquire), then stage/chain/project/epilogue.
//      Deadlock-free: 76.5KB LDS -> 2 WG/CU -> all 256 WGs co-resident.
//      Poison-safe: flag zeroed by K1 (prior dispatch, same stream).

// ---- 32x32 fp32 matmul, A,B,C in LDS, 256 threads, thread = (row j, col-quad kq)
__device__ __forceinline__ void mm32(const float* __restrict__ A,
                                     const float* __restrict__ B,
                                     float* __restrict__ C, int tid) {
    const int j = tid >> 3;      // 0..31 output row
    const int kq = tid & 7;      // 0..7  -> output cols 4kq..4kq+3
    float a[32];
    const float4* __restrict__ A4 = (const float4*)(A + j * 32);
#pragma unroll
    for (int t = 0; t < 8; ++t) {
        float4 v = A4[t];
        a[4 * t + 0] = v.x; a[4 * t + 1] = v.y;
        a[4 * t + 2] = v.z; a[4 * t + 3] = v.w;
    }
    const float4* __restrict__ B4 = (const float4*)B;
    float4 acc0 = make_float4(0.f, 0.f, 0.f, 0.f);
    float4 acc1 = make_float4(0.f, 0.f, 0.f, 0.f);
#pragma unroll
    for (int m = 0; m < 16; ++m) {
        float4 b0 = B4[m * 8 + kq];
        float4 b1 = B4[(m + 16) * 8 + kq];
        acc0.x = fmaf(a[m], b0.x, acc0.x);
        acc0.y = fmaf(a[m], b0.y, acc0.y);
        acc0.z = fmaf(a[m], b0.z, acc0.z);
        acc0.w = fmaf(a[m], b0.w, acc0.w);
        acc1.x = fmaf(a[m + 16], b1.x, acc1.x);
        acc1.y = fmaf(a[m + 16], b1.y, acc1.y);
        acc1.z = fmaf(a[m + 16], b1.z, acc1.z);
        acc1.w = fmaf(a[m + 16], b1.w, acc1.w);
    }
    float4 acc;
    acc.x = acc0.x + acc1.x; acc.y = acc0.y + acc1.y;
    acc.z = acc0.z + acc1.z; acc.w = acc0.w + acc1.w;
    ((float4*)(C + j * 32))[kq] = acc;
}

// ---- K1: 256 WGs. p-products for 16 rows, then tree L1. Zeroes flag.
__global__ __launch_bounds__(256) void k1(const float* __restrict__ cores,
                                          const float* __restrict__ inputs,
                                          float* __restrict__ l1,
                                          float* __restrict__ p,
                                          int* __restrict__ flag) {
    __shared__ __align__(16) float c[4 * 1024];
    __shared__ __align__(16) float ping[1024];
    __shared__ __align__(16) float pong[1024];
    const int tid = threadIdx.x;
    const int s = blockIdx.x;
    const int lane = tid & 63;
    const int wid = tid >> 6;

    if (s == 0 && tid == 0) *flag = 0;   // visible to k4f at dispatch boundary

    // stage cores -> LDS
    const float4* src = (const float4*)(cores + (size_t)s * 4096);
    float4* cd = (float4*)c;
#pragma unroll
    for (int t = 0; t < 4; ++t) cd[tid + 256 * t] = src[tid + 256 * t];

    // p-products: 4 rows per wave, consumed immediately
    float prs[4];
#pragma unroll
    for (int rr = 0; rr < 4; ++rr) {
        const int row = s * 16 + wid * 4 + rr;
        const float4* in4 = (const float4*)(inputs + (size_t)row * 1024);
        float4 x0 = in4[lane];
        float4 x1 = in4[lane + 64];
        float4 x2 = in4[lane + 128];
        float4 x3 = in4[lane + 192];
        prs[rr] = ((x0.x * x0.y) * (x0.z * x0.w)) * ((x1.x * x1.y) * (x1.z * x1.w)) *
                  ((x2.x * x2.y) * (x2.z * x2.w)) * ((x3.x * x3.y) * (x3.z * x3.w));
    }
#pragma unroll
    for (int rr = 0; rr < 4; ++rr) {
        float pr = prs[rr];
#pragma unroll
        for (int msk = 1; msk < 64; msk <<= 1) pr *= __shfl_xor(pr, msk);
        if (lane == 0) p[s * 16 + wid * 4 + rr] = pr;
    }

    __syncthreads();
    mm32(c, c + 1024, ping, tid);
    __syncthreads();
    mm32(ping, c + 2048, pong, tid);
    __syncthreads();
    mm32(pong, c + 3072, ping, tid);
    __syncthreads();
    ((float4*)(l1 + (size_t)s * 1024))[tid] = ((const float4*)ping)[tid];
}

// ---- K4F: fused k2+k4. 256 WGs.
__global__ __launch_bounds__(256) void k4f(const float* __restrict__ l1,
                                           float* __restrict__ l2,
                                           int* __restrict__ flag,
                                           const float* __restrict__ proj,
                                           const float* __restrict__ p,
                                           const float* __restrict__ bias,
                                           float* __restrict__ out) {
    __shared__ __align__(16) float M[16 * 1024];
    __shared__ __align__(16) float ping[1024];
    __shared__ __align__(16) float pong[1024];
    __shared__ __align__(16) float qL[512];
    __shared__ __align__(16) float bL[512];
    __shared__ float pL[16];
    __shared__ float w[32];
    const int tid = threadIdx.x;
    const int s = blockIdx.x;

    // ---- producer phase: WGs 0..15 compute l2[s] = prod of l1[16s..16s+15]
    if (s < 16) {                      // workgroup-uniform branch: barriers legal
        const float4* srcP = (const float4*)(l1 + (size_t)s * 16384);
        float4* Md = (float4*)M;
#pragma unroll
        for (int t = 0; t < 16; ++t) Md[tid + 256 * t] = srcP[tid + 256 * t];
        __syncthreads();
        mm32(M, M + 1024, ping, tid);
        __syncthreads();
        float* A = ping;
        float* C = pong;
        for (int t = 2; t < 16; ++t) {
            mm32(A, M + t * 1024, C, tid);
            __syncthreads();
            float* tmp = A; A = C; C = tmp;
        }
        ((float4*)(l2 + (size_t)s * 1024))[tid] = ((const float4*)A)[tid];
        __threadfence();               // agent-scope release of the 4KB result
        __syncthreads();               // all lanes' stores+fences before signal
        if (tid == 0)
            __hip_atomic_fetch_add(flag, 1, __ATOMIC_RELEASE,
                                   __HIP_MEMORY_SCOPE_AGENT);
    }

    // ---- all WGs: prefetch bias/p while producers finish
    if (tid < 128) ((float4*)bL)[tid] = ((const float4*)bias)[tid];
    if (tid < 16) pL[tid] = p[s * 16 + tid];

    if (tid == 0) {
        while (__hip_atomic_load(flag, __ATOMIC_ACQUIRE,
                                 __HIP_MEMORY_SCOPE_AGENT) < 16)
            __builtin_amdgcn_s_sleep(2);
    }
    __syncthreads();
    __threadfence();                   // acquire side: no stale l2 lines

    // ---- stage the 16 chain matrices (64 KB)
    const float4* src = (const float4*)l2;
    float4* Md = (float4*)M;
#pragma unroll
    for (int t = 0; t < 16; ++t) Md[tid + 256 * t] = src[tid + 256 * t];
    __syncthreads();

    // ---- wave 0: chain w^T = 1^T M0..M15 (lane k holds v[k]; 4-way ILP)
    if (tid < 64) {
        const int k = tid & 31;
        float v = 1.0f;
        for (int sm = 0; sm < 16; ++sm) {
            const float* mat = M + sm * 1024 + k;
            float a0 = 0.f, a1 = 0.f, a2 = 0.f, a3 = 0.f;
#pragma unroll
            for (int j = 0; j < 8; ++j) {
                a0 = fmaf(__shfl(v, j),      mat[32 * j],        a0);
                a1 = fmaf(__shfl(v, j + 8),  mat[32 * (j + 8)],  a1);
                a2 = fmaf(__shfl(v, j + 16), mat[32 * (j + 16)], a2);
                a3 = fmaf(__shfl(v, j + 24), mat[32 * (j + 24)], a3);
            }
            v = (a0 + a1) + (a2 + a3);
        }
        if (tid < 32) w[k] = v;
    }
    __syncthreads();

    // ---- projection: qL[o] = sum_j w[j]*proj[j,o]
    if (tid < 128) {
        const float4* P4 = (const float4*)proj;
        float4 acc = make_float4(0.f, 0.f, 0.f, 0.f);
#pragma unroll
        for (int j = 0; j < 32; ++j) {
            float wj = w[j];
            float4 pv = P4[j * 128 + tid];
            acc.x = fmaf(wj, pv.x, acc.x);
            acc.y = fmaf(wj, pv.y, acc.y);
            acc.z = fmaf(wj, pv.z, acc.z);
            acc.w = fmaf(wj, pv.w, acc.w);
        }
        ((float4*)qL)[tid] = acc;
    }
    __syncthreads();

    // ---- epilogue: 16 rows/WG, 32 threads/row, 4 float4/thread
    const float4* q4 = (const float4*)qL;
    const float4* b4 = (const float4*)bL;
#pragma unroll
    for (int rb = 0; rb < 2; ++rb) {
        const int r8 = rb * 8 + (tid >> 5);
        const int row = s * 16 + r8;
        const float pr = pL[r8];
        float4* o4 = (float4*)(out + (size_t)row * 512);
#pragma unroll
        for (int u = 0; u < 4; ++u) {
            const int c4 = u * 32 + (tid & 31);
            float4 qq = q4[c4];
            float4 bb = b4[c4];
            float4 r;
            r.x = fmaf(pr, qq.x, bb.x);
            r.y = fmaf(pr, qq.y, bb.y);
            r.z = fmaf(pr, qq.z, bb.z);
            r.w = fmaf(pr, qq.w, bb.w);
            o4[c4] = r;
        }
    }
}

extern "C" void kernel_launch(void* const* d_in, const int* in_sizes, int n_in,
                              void* d_out, int out_size, void* d_ws, size_t ws_size,
                              hipStream_t stream) {
    const float* inputs = (const float*)d_in[0];   // [4096,1024]
    const float* cores  = (const float*)d_in[1];   // [1024,32,32]
    const float* proj   = (const float*)d_in[2];   // [32,512]
    const float* bias   = (const float*)d_in[3];   // [512]
    float* out = (float*)d_out;                    // [4096,512]
    float* wsf = (float*)d_ws;
    float* l1 = wsf;                                 // 256*1024 floats
    float* l2 = wsf + 256 * 1024;                    // 16*1024 floats
    float* p  = wsf + 256 * 1024 + 16 * 1024;        // 4096 floats
    int* flag = (int*)(wsf + 256 * 1024 + 16 * 1024 + 4096 + 64);  // own line

    k1<<<256, 256, 0, stream>>>(cores, inputs, l1, p, flag);
    k4f<<<256, 256, 0, stream>>>(l1, l2, flag, proj, p, bias, out);
}

// Round 9
// 94.212 us; speedup vs baseline: 1.3354x; 1.3354x over previous
//
#include <hip/hip_runtime.h>

// out[b,o] = p[b]*q[o] + bias[o]
//   p[b] = prod_i inputs[b,i];  q = (1^T * prod_i C_i) @ projection
// Empirical law (R4 k3=61us/1WG, R8 k4f=58us/spin): any phase where most of
// the chip idles costs 30-60us regardless of work. So: every dispatch is
// 256 WGs, no spin-waits, no tiny grids. Redundant compute is free; idle isn't.
// K1:  256 WGs: tree L1 (1024 cores -> 256 mats) + p-products.
// K2B: 256 WGs: WG s computes level-2 product of segment s&15 (16x redundant,
//      keeps all CUs busy); writes own slot l2big[s]; k4 reads slots 0-15.
// K4:  256 WGs: stage 16 mats, wave-0 ILP chain, project, 16 rows/WG epilogue.

// ---- 32x32 fp32 matmul, A,B,C in LDS, 256 threads, thread = (row j, col-quad kq)
__device__ __forceinline__ void mm32(const float* __restrict__ A,
                                     const float* __restrict__ B,
                                     float* __restrict__ C, int tid) {
    const int j = tid >> 3;      // 0..31 output row
    const int kq = tid & 7;      // 0..7  -> output cols 4kq..4kq+3
    float a[32];
    const float4* __restrict__ A4 = (const float4*)(A + j * 32);
#pragma unroll
    for (int t = 0; t < 8; ++t) {
        float4 v = A4[t];
        a[4 * t + 0] = v.x; a[4 * t + 1] = v.y;
        a[4 * t + 2] = v.z; a[4 * t + 3] = v.w;
    }
    const float4* __restrict__ B4 = (const float4*)B;
    float4 acc0 = make_float4(0.f, 0.f, 0.f, 0.f);
    float4 acc1 = make_float4(0.f, 0.f, 0.f, 0.f);
#pragma unroll
    for (int m = 0; m < 16; ++m) {
        float4 b0 = B4[m * 8 + kq];
        float4 b1 = B4[(m + 16) * 8 + kq];
        acc0.x = fmaf(a[m], b0.x, acc0.x);
        acc0.y = fmaf(a[m], b0.y, acc0.y);
        acc0.z = fmaf(a[m], b0.z, acc0.z);
        acc0.w = fmaf(a[m], b0.w, acc0.w);
        acc1.x = fmaf(a[m + 16], b1.x, acc1.x);
        acc1.y = fmaf(a[m + 16], b1.y, acc1.y);
        acc1.z = fmaf(a[m + 16], b1.z, acc1.z);
        acc1.w = fmaf(a[m + 16], b1.w, acc1.w);
    }
    float4 acc;
    acc.x = acc0.x + acc1.x; acc.y = acc0.y + acc1.y;
    acc.z = acc0.z + acc1.z; acc.w = acc0.w + acc1.w;
    ((float4*)(C + j * 32))[kq] = acc;
}

// ---- K1: 256 WGs. p-products for 16 rows (consumed immediately), then tree L1.
__global__ __launch_bounds__(256) void k1(const float* __restrict__ cores,
                                          const float* __restrict__ inputs,
                                          float* __restrict__ l1,
                                          float* __restrict__ p) {
    __shared__ __align__(16) float c[4 * 1024];
    __shared__ __align__(16) float ping[1024];
    __shared__ __align__(16) float pong[1024];
    const int tid = threadIdx.x;
    const int s = blockIdx.x;
    const int lane = tid & 63;
    const int wid = tid >> 6;

    // stage cores -> LDS
    const float4* src = (const float4*)(cores + (size_t)s * 4096);
    float4* cd = (float4*)c;
#pragma unroll
    for (int t = 0; t < 4; ++t) cd[tid + 256 * t] = src[tid + 256 * t];

    // p-products: 4 rows per wave, consumed immediately
    float prs[4];
#pragma unroll
    for (int rr = 0; rr < 4; ++rr) {
        const int row = s * 16 + wid * 4 + rr;
        const float4* in4 = (const float4*)(inputs + (size_t)row * 1024);
        float4 x0 = in4[lane];
        float4 x1 = in4[lane + 64];
        float4 x2 = in4[lane + 128];
        float4 x3 = in4[lane + 192];
        prs[rr] = ((x0.x * x0.y) * (x0.z * x0.w)) * ((x1.x * x1.y) * (x1.z * x1.w)) *
                  ((x2.x * x2.y) * (x2.z * x2.w)) * ((x3.x * x3.y) * (x3.z * x3.w));
    }
#pragma unroll
    for (int rr = 0; rr < 4; ++rr) {
        float pr = prs[rr];
#pragma unroll
        for (int msk = 1; msk < 64; msk <<= 1) pr *= __shfl_xor(pr, msk);
        if (lane == 0) p[s * 16 + wid * 4 + rr] = pr;
    }

    __syncthreads();
    mm32(c, c + 1024, ping, tid);
    __syncthreads();
    mm32(ping, c + 2048, pong, tid);
    __syncthreads();
    mm32(pong, c + 3072, ping, tid);
    __syncthreads();
    ((float4*)(l1 + (size_t)s * 1024))[tid] = ((const float4*)ping)[tid];
}

// ---- K2B: 256 WGs (16x redundant). WG s: product of l1 segment (s&15),
//           written to its OWN slot l2big[s] (observable -> no DCE; no races).
__global__ __launch_bounds__(256) void k2b(const float* __restrict__ l1,
                                           float* __restrict__ l2big) {
    __shared__ __align__(16) float m[16 * 1024];
    __shared__ __align__(16) float ping[1024];
    __shared__ __align__(16) float pong[1024];
    const int tid = threadIdx.x;
    const int s = blockIdx.x;
    const int seg = s & 15;
    const float4* src = (const float4*)(l1 + (size_t)seg * 16384);
    float4* md = (float4*)m;
#pragma unroll
    for (int t = 0; t < 16; ++t) md[tid + 256 * t] = src[tid + 256 * t];
    __syncthreads();
    mm32(m, m + 1024, ping, tid);
    __syncthreads();
    float* A = ping;
    float* C = pong;
    for (int t = 2; t < 16; ++t) {
        mm32(A, m + t * 1024, C, tid);
        __syncthreads();
        float* tmp = A; A = C; C = tmp;
    }
    ((float4*)(l2big + (size_t)s * 1024))[tid] = ((const float4*)A)[tid];
}

// ---- K4: 256 WGs. Stage 16 mats + bias/p, wave-0 ILP chain, project q,
//          then out[row,:] = p[row]*q + bias for 16 rows.
__global__ __launch_bounds__(256) void k4(const float* __restrict__ l2,
                                          const float* __restrict__ proj,
                                          const float* __restrict__ p,
                                          const float* __restrict__ bias,
                                          float* __restrict__ out) {
    __shared__ __align__(16) float M[16 * 1024];
    __shared__ __align__(16) float qL[512];
    __shared__ __align__(16) float bL[512];
    __shared__ float pL[16];
    __shared__ float w[32];
    const int tid = threadIdx.x;
    const int s = blockIdx.x;

    // stage the 16 chain matrices (64 KB, slots 0-15 = segments 0-15 in order)
    const float4* src = (const float4*)l2;
    float4* Md = (float4*)M;
#pragma unroll
    for (int t = 0; t < 16; ++t) Md[tid + 256 * t] = src[tid + 256 * t];
    if (tid < 128) ((float4*)bL)[tid] = ((const float4*)bias)[tid];
    if (tid < 16) pL[tid] = p[s * 16 + tid];
    __syncthreads();

    // wave 0: chain w^T = 1^T M0..M15. Lane k holds v[k] (lanes 32-63 dup).
    // 4 independent 8-fma chains per step. mat[32j+k]: lane k -> bank k, free.
    if (tid < 64) {
        const int k = tid & 31;
        float v = 1.0f;
        for (int sm = 0; sm < 16; ++sm) {
            const float* mat = M + sm * 1024 + k;
            float a0 = 0.f, a1 = 0.f, a2 = 0.f, a3 = 0.f;
#pragma unroll
            for (int j = 0; j < 8; ++j) {
                a0 = fmaf(__shfl(v, j),      mat[32 * j],        a0);
                a1 = fmaf(__shfl(v, j + 8),  mat[32 * (j + 8)],  a1);
                a2 = fmaf(__shfl(v, j + 16), mat[32 * (j + 16)], a2);
                a3 = fmaf(__shfl(v, j + 24), mat[32 * (j + 24)], a3);
            }
            v = (a0 + a1) + (a2 + a3);
        }
        if (tid < 32) w[k] = v;
    }
    __syncthreads();

    // projection: qL[o] = sum_j w[j]*proj[j,o]; 128 threads x 1 float4
    if (tid < 128) {
        const float4* P4 = (const float4*)proj;
        float4 acc = make_float4(0.f, 0.f, 0.f, 0.f);
#pragma unroll
        for (int j = 0; j < 32; ++j) {
            float wj = w[j];
            float4 pv = P4[j * 128 + tid];
            acc.x = fmaf(wj, pv.x, acc.x);
            acc.y = fmaf(wj, pv.y, acc.y);
            acc.z = fmaf(wj, pv.z, acc.z);
            acc.w = fmaf(wj, pv.w, acc.w);
        }
        ((float4*)qL)[tid] = acc;
    }
    __syncthreads();

    // epilogue: 16 rows/WG (two blocks of 8), 32 threads/row, 4 float4/thread
    const float4* q4 = (const float4*)qL;
    const float4* b4 = (const float4*)bL;
#pragma unroll
    for (int rb = 0; rb < 2; ++rb) {
        const int r8 = rb * 8 + (tid >> 5);
        const int row = s * 16 + r8;
        const float pr = pL[r8];
        float4* o4 = (float4*)(out + (size_t)row * 512);
#pragma unroll
        for (int u = 0; u < 4; ++u) {
            const int c4 = u * 32 + (tid & 31);
            float4 qq = q4[c4];
            float4 bb = b4[c4];
            float4 r;
            r.x = fmaf(pr, qq.x, bb.x);
            r.y = fmaf(pr, qq.y, bb.y);
            r.z = fmaf(pr, qq.z, bb.z);
            r.w = fmaf(pr, qq.w, bb.w);
            o4[c4] = r;
        }
    }
}

extern "C" void kernel_launch(void* const* d_in, const int* in_sizes, int n_in,
                              void* d_out, int out_size, void* d_ws, size_t ws_size,
                              hipStream_t stream) {
    const float* inputs = (const float*)d_in[0];   // [4096,1024]
    const float* cores  = (const float*)d_in[1];   // [1024,32,32]
    const float* proj   = (const float*)d_in[2];   // [32,512]
    const float* bias   = (const float*)d_in[3];   // [512]
    float* out = (float*)d_out;                    // [4096,512]
    float* wsf = (float*)d_ws;
    float* l1    = wsf;                              // 256*1024 floats
    float* l2big = wsf + 256 * 1024;                 // 256*1024 floats
    float* p     = wsf + 512 * 1024;                 // 4096 floats

    k1<<<256, 256, 0, stream>>>(cores, inputs, l1, p);
    k2b<<<256, 256, 0, stream>>>(l1, l2big);
    k4<<<256, 256, 0, stream>>>(l2big, proj, p, bias, out);
}